// Round 2
// baseline (704.187 us; speedup 1.0000x reference)
//
#include <hip/hip_runtime.h>

#define N_DIM   3072
#define BATCH_N 8192
#define K_FIX   30

// ---------------- Path 1: specialized fast kernel (diag_pos[i] == i) --------
// Block: RC=256 output cols x BR=32 batch rows. V band slice staged in LDS,
// pre-shifted per diagonal so the inner loop is one aligned ds_read_b128 per
// diagonal, shared across 2 batch rows (8 FMAs per 16B LDS read).
// Per-thread: 2 x-windows (36 floats each) in registers, statically indexed.
#define RC      256
#define BR      32
#define VROWS   K_FIX
#define VW_W    (RC + 32)            // 288 floats per LDS row
#define NRT     (N_DIM / RC)         // 12 r-tiles

__global__ __launch_bounds__(256, 4)
void fc_diag_fast(const float* __restrict__ x, const float* __restrict__ V,
                  const int* __restrict__ dp, float* __restrict__ out)
{
    // Wave-uniform pattern check (uniform across block -> safe w.r.t. barrier).
    bool ok = true;
    #pragma unroll
    for (int i = 0; i < K_FIX; ++i) ok = ok && (dp[i] == i);
    if (!ok) return;

    __shared__ float Vs[VROWS * VW_W];   // 34.56 KB

    const int rtile = blockIdx.x % NRT;
    const int btile = blockIdx.x / NRT;
    const int C0 = rtile * RC;
    const int b0 = btile * BR;

    // Stage pre-shifted V: Vs[i][m] = V[i][(C0 + m - 32 - i) mod N].
    // Then for output col c0+j, diagonal i: V[i][(c0+j-i) mod N] = Vs[i][c0l+32+j].
    for (int t = (int)threadIdx.x; t < VROWS * VW_W; t += 256) {
        const int i = t / VW_W;
        const int m = t - i * VW_W;
        int col = C0 + m - 32 - i;           // range [-61, 3071]
        if (col < 0) col += N_DIM;
        Vs[t] = V[(size_t)i * N_DIM + col];
    }
    __syncthreads();

    const int cg  = (int)threadIdx.x & 63;   // col group: 64 x 4 cols = 256
    const int rg  = (int)threadIdx.x >> 6;   // row group: 4 x 8 rows = 32
    const int c0l = cg * 4;
    const float* vbase = &Vs[c0l + 32];      // 16B-aligned, row stride VW_W

    for (int rr = 0; rr < 8; rr += 2) {
        const int b = b0 + rg * 8 + rr;
        const float* xb0 = x + (size_t)b * N_DIM;
        const float* xb1 = xb0 + N_DIM;

        // x windows for cols [c0-32, c0+4), wrapped; all float4 aligned.
        float X0[36], X1[36];
        #pragma unroll
        for (int k = 0; k < 9; ++k) {
            int g = C0 + c0l - 32 + 4 * k;   // range [-32, 3068]
            if (g < 0) g += N_DIM;
            const float4 a = *reinterpret_cast<const float4*>(xb0 + g);
            const float4 c = *reinterpret_cast<const float4*>(xb1 + g);
            X0[4*k+0] = a.x; X0[4*k+1] = a.y; X0[4*k+2] = a.z; X0[4*k+3] = a.w;
            X1[4*k+0] = c.x; X1[4*k+1] = c.y; X1[4*k+2] = c.z; X1[4*k+3] = c.w;
        }

        float a00 = 0.f, a01 = 0.f, a02 = 0.f, a03 = 0.f;
        float a10 = 0.f, a11 = 0.f, a12 = 0.f, a13 = 0.f;
        #pragma unroll
        for (int i = 0; i < K_FIX; ++i) {
            const float4 vw = *reinterpret_cast<const float4*>(vbase + i * VW_W);
            // X index 32+j-i is a compile-time constant in [3,35].
            a00 = fmaf(X0[32 - i], vw.x, a00);
            a01 = fmaf(X0[33 - i], vw.y, a01);
            a02 = fmaf(X0[34 - i], vw.z, a02);
            a03 = fmaf(X0[35 - i], vw.w, a03);
            a10 = fmaf(X1[32 - i], vw.x, a10);
            a11 = fmaf(X1[33 - i], vw.y, a11);
            a12 = fmaf(X1[34 - i], vw.z, a12);
            a13 = fmaf(X1[35 - i], vw.w, a13);
        }

        float4 o0; o0.x = a00; o0.y = a01; o0.z = a02; o0.w = a03;
        float4 o1; o1.x = a10; o1.y = a11; o1.z = a12; o1.w = a13;
        *reinterpret_cast<float4*>(out + (size_t)b * N_DIM + C0 + c0l) = o0;
        *reinterpret_cast<float4*>(out + (size_t)(b + 1) * N_DIM + C0 + c0l) = o1;
    }
}

// ---------------- Path 2: general K=30 (arbitrary diag values) --------------
#define G_NBT   128
#define G_BROWS (BATCH_N / G_NBT)    // 64

__global__ __launch_bounds__(256)
void fc_diag_general30(const float* __restrict__ x, const float* __restrict__ V,
                       const int* __restrict__ dp, float* __restrict__ out)
{
    bool contig = true;
    #pragma unroll
    for (int i = 0; i < K_FIX; ++i) contig = contig && (dp[i] == i);
    if (contig) return;  // fast kernel handled it

    const int NRT2 = N_DIM / 256;    // 12 r-tiles
    const int rtile = blockIdx.x % NRT2;
    const int btile = blockIdx.x / NRT2;
    const int r  = rtile * 256 + (int)threadIdx.x;
    const int b0 = btile * G_BROWS;

    int   CI[K_FIX];
    float VW[K_FIX];
    #pragma unroll
    for (int i = 0; i < K_FIX; ++i) {
        int d = dp[i] % N_DIM; if (d < 0) d += N_DIM;
        int c = r - d; if (c < 0) c += N_DIM;
        CI[i] = c;
        VW[i] = V[(size_t)d * N_DIM + c];
    }

    for (int b = b0; b < b0 + G_BROWS; b += 2) {
        const float* xb0 = x + (size_t)b * N_DIM;
        const float* xb1 = xb0 + N_DIM;
        float a0 = 0.f, a1 = 0.f;
        #pragma unroll
        for (int i = 0; i < K_FIX; ++i) {
            const float w = VW[i]; const int c = CI[i];
            a0 = fmaf(xb0[c], w, a0);
            a1 = fmaf(xb1[c], w, a1);
        }
        out[(size_t)b * N_DIM + r]       = a0;
        out[(size_t)(b + 1) * N_DIM + r] = a1;
    }
}

// ---------------- Path 3: naive fallback for K != 30 ------------------------
__global__ void fc_diag_naive(const float* __restrict__ x, const float* __restrict__ V,
                              const int* __restrict__ dp, int K, float* __restrict__ out)
{
    size_t idx   = (size_t)blockIdx.x * blockDim.x + threadIdx.x;
    size_t total = (size_t)BATCH_N * N_DIM;
    size_t step  = (size_t)gridDim.x * blockDim.x;
    for (; idx < total; idx += step) {
        int b = (int)(idx / N_DIM), r = (int)(idx % N_DIM);
        float acc = 0.f;
        for (int i = 0; i < K; ++i) {
            int d = dp[i] % N_DIM; if (d < 0) d += N_DIM;
            int c = r - d; if (c < 0) c += N_DIM;
            acc = fmaf(x[(size_t)b * N_DIM + c], V[(size_t)d * N_DIM + c], acc);
        }
        out[idx] = acc;
    }
}

extern "C" void kernel_launch(void* const* d_in, const int* in_sizes, int n_in,
                              void* d_out, int out_size, void* d_ws, size_t ws_size,
                              hipStream_t stream)
{
    const float* x  = (const float*)d_in[0];
    const float* V  = (const float*)d_in[1];
    const int*   dp = (const int*)d_in[2];
    float* out = (float*)d_out;
    const int K = in_sizes[2];

    if (K == K_FIX) {
        fc_diag_fast<<<dim3(NRT * (BATCH_N / BR)), dim3(256), 0, stream>>>(x, V, dp, out);
        fc_diag_general30<<<dim3((N_DIM / 256) * G_NBT), dim3(256), 0, stream>>>(x, V, dp, out);
    } else {
        fc_diag_naive<<<dim3(2048), dim3(256), 0, stream>>>(x, V, dp, K, out);
    }
}

// Round 3
// 140.866 us; speedup vs baseline: 4.9990x; 4.9990x over previous
//
#include <hip/hip_runtime.h>

#define N_DIM   3072
#define BATCH_N 8192
#define K_FIX   30

// ---------------- Path 1: specialized fast kernel (diag_pos[i] == i) --------
// Block: RC=256 output cols x BR=32 batch rows. V band slice staged in LDS,
// pre-shifted per diagonal so the inner loop is one aligned ds_read_b128 per
// diagonal, shared across 2 batch rows (8 FMAs per 16B LDS read).
// Per-thread: 2 x-windows (36 floats each) in registers, statically indexed.
// NOTE: no min-waves clamp in __launch_bounds__ -- R2's (256,4) forced a
// 64-VGPR cap and spilled the ~100-float working set to scratch (2.3 GB of
// FETCH+WRITE observed). Let the allocator take ~110-130 VGPRs.
#define RC      256
#define BR      32
#define VROWS   K_FIX
#define VW_W    (RC + 32)            // 288 floats per LDS row
#define NRT     (N_DIM / RC)         // 12 r-tiles

__global__ __launch_bounds__(256)
void fc_diag_fast(const float* __restrict__ x, const float* __restrict__ V,
                  const int* __restrict__ dp, float* __restrict__ out)
{
    // Wave-uniform pattern check (uniform across block -> safe w.r.t. barrier).
    bool ok = true;
    #pragma unroll
    for (int i = 0; i < K_FIX; ++i) ok = ok && (dp[i] == i);
    if (!ok) return;

    __shared__ float Vs[VROWS * VW_W];   // 34.56 KB

    const int rtile = blockIdx.x % NRT;
    const int btile = blockIdx.x / NRT;
    const int C0 = rtile * RC;
    const int b0 = btile * BR;

    // Stage pre-shifted V: Vs[i][m] = V[i][(C0 + m - 32 - i) mod N].
    // Then for output col c0+j, diagonal i: V[i][(c0+j-i) mod N] = Vs[i][c0l+32+j].
    for (int t = (int)threadIdx.x; t < VROWS * VW_W; t += 256) {
        const int i = t / VW_W;
        const int m = t - i * VW_W;
        int col = C0 + m - 32 - i;           // range [-61, 3071]
        if (col < 0) col += N_DIM;
        Vs[t] = V[(size_t)i * N_DIM + col];
    }
    __syncthreads();

    const int cg  = (int)threadIdx.x & 63;   // col group: 64 x 4 cols = 256
    const int rg  = (int)threadIdx.x >> 6;   // row group: 4 x 8 rows = 32
    const int c0l = cg * 4;
    const float* vbase = &Vs[c0l + 32];      // 16B-aligned, row stride VW_W

    for (int rr = 0; rr < 8; rr += 2) {
        const int b = b0 + rg * 8 + rr;
        const float* xb0 = x + (size_t)b * N_DIM;
        const float* xb1 = xb0 + N_DIM;

        // x windows for cols [c0-32, c0+4), wrapped; all float4 aligned.
        // 18 independent loads -- with registers unclamped these issue
        // back-to-back (memory-level parallelism).
        float X0[36], X1[36];
        #pragma unroll
        for (int k = 0; k < 9; ++k) {
            int g = C0 + c0l - 32 + 4 * k;   // range [-32, 3068]
            if (g < 0) g += N_DIM;
            const float4 a = *reinterpret_cast<const float4*>(xb0 + g);
            const float4 c = *reinterpret_cast<const float4*>(xb1 + g);
            X0[4*k+0] = a.x; X0[4*k+1] = a.y; X0[4*k+2] = a.z; X0[4*k+3] = a.w;
            X1[4*k+0] = c.x; X1[4*k+1] = c.y; X1[4*k+2] = c.z; X1[4*k+3] = c.w;
        }

        float a00 = 0.f, a01 = 0.f, a02 = 0.f, a03 = 0.f;
        float a10 = 0.f, a11 = 0.f, a12 = 0.f, a13 = 0.f;
        #pragma unroll
        for (int i = 0; i < K_FIX; ++i) {
            const float4 vw = *reinterpret_cast<const float4*>(vbase + i * VW_W);
            // X index 32+j-i is a compile-time constant in [3,35].
            a00 = fmaf(X0[32 - i], vw.x, a00);
            a01 = fmaf(X0[33 - i], vw.y, a01);
            a02 = fmaf(X0[34 - i], vw.z, a02);
            a03 = fmaf(X0[35 - i], vw.w, a03);
            a10 = fmaf(X1[32 - i], vw.x, a10);
            a11 = fmaf(X1[33 - i], vw.y, a11);
            a12 = fmaf(X1[34 - i], vw.z, a12);
            a13 = fmaf(X1[35 - i], vw.w, a13);
        }

        float4 o0; o0.x = a00; o0.y = a01; o0.z = a02; o0.w = a03;
        float4 o1; o1.x = a10; o1.y = a11; o1.z = a12; o1.w = a13;
        *reinterpret_cast<float4*>(out + (size_t)b * N_DIM + C0 + c0l) = o0;
        *reinterpret_cast<float4*>(out + (size_t)(b + 1) * N_DIM + C0 + c0l) = o1;
    }
}

// ---------------- Path 2: general K=30 (arbitrary diag values) --------------
#define G_NBT   128
#define G_BROWS (BATCH_N / G_NBT)    // 64

__global__ __launch_bounds__(256)
void fc_diag_general30(const float* __restrict__ x, const float* __restrict__ V,
                       const int* __restrict__ dp, float* __restrict__ out)
{
    bool contig = true;
    #pragma unroll
    for (int i = 0; i < K_FIX; ++i) contig = contig && (dp[i] == i);
    if (contig) return;  // fast kernel handled it

    const int NRT2 = N_DIM / 256;    // 12 r-tiles
    const int rtile = blockIdx.x % NRT2;
    const int btile = blockIdx.x / NRT2;
    const int r  = rtile * 256 + (int)threadIdx.x;
    const int b0 = btile * G_BROWS;

    int   CI[K_FIX];
    float VW[K_FIX];
    #pragma unroll
    for (int i = 0; i < K_FIX; ++i) {
        int d = dp[i] % N_DIM; if (d < 0) d += N_DIM;
        int c = r - d; if (c < 0) c += N_DIM;
        CI[i] = c;
        VW[i] = V[(size_t)d * N_DIM + c];
    }

    for (int b = b0; b < b0 + G_BROWS; b += 2) {
        const float* xb0 = x + (size_t)b * N_DIM;
        const float* xb1 = xb0 + N_DIM;
        float a0 = 0.f, a1 = 0.f;
        #pragma unroll
        for (int i = 0; i < K_FIX; ++i) {
            const float w = VW[i]; const int c = CI[i];
            a0 = fmaf(xb0[c], w, a0);
            a1 = fmaf(xb1[c], w, a1);
        }
        out[(size_t)b * N_DIM + r]       = a0;
        out[(size_t)(b + 1) * N_DIM + r] = a1;
    }
}

// ---------------- Path 3: naive fallback for K != 30 ------------------------
__global__ void fc_diag_naive(const float* __restrict__ x, const float* __restrict__ V,
                              const int* __restrict__ dp, int K, float* __restrict__ out)
{
    size_t idx   = (size_t)blockIdx.x * blockDim.x + threadIdx.x;
    size_t total = (size_t)BATCH_N * N_DIM;
    size_t step  = (size_t)gridDim.x * blockDim.x;
    for (; idx < total; idx += step) {
        int b = (int)(idx / N_DIM), r = (int)(idx % N_DIM);
        float acc = 0.f;
        for (int i = 0; i < K; ++i) {
            int d = dp[i] % N_DIM; if (d < 0) d += N_DIM;
            int c = r - d; if (c < 0) c += N_DIM;
            acc = fmaf(x[(size_t)b * N_DIM + c], V[(size_t)d * N_DIM + c], acc);
        }
        out[idx] = acc;
    }
}

extern "C" void kernel_launch(void* const* d_in, const int* in_sizes, int n_in,
                              void* d_out, int out_size, void* d_ws, size_t ws_size,
                              hipStream_t stream)
{
    const float* x  = (const float*)d_in[0];
    const float* V  = (const float*)d_in[1];
    const int*   dp = (const int*)d_in[2];
    float* out = (float*)d_out;
    const int K = in_sizes[2];

    if (K == K_FIX) {
        fc_diag_fast<<<dim3(NRT * (BATCH_N / BR)), dim3(256), 0, stream>>>(x, V, dp, out);
        fc_diag_general30<<<dim3((N_DIM / 256) * G_NBT), dim3(256), 0, stream>>>(x, V, dp, out);
    } else {
        fc_diag_naive<<<dim3(2048), dim3(256), 0, stream>>>(x, V, dp, K, out);
    }
}

// Round 4
// 109.871 us; speedup vs baseline: 6.4092x; 1.2821x over previous
//
#include <hip/hip_runtime.h>

#define N_DIM   3072
#define BATCH_N 8192
#define K_FIX   30

// ---------------- Path 1: specialized fast kernel (diag_pos[i] == i) --------
// Block: RC=256 output cols x BR=32 batch rows, 256 threads.
// cg = tid&63 -> 4 consecutive cols; rg = tid>>6 -> 8-row group, processed as
// 2 iterations of 4 rows. Each V ds_read_b128 feeds 16 FMAs (4 rows x 4 cols),
// halving LDS traffic vs R3 (aggregate ~14.5 us < 24 us HBM floor).
// Per-thread: 4 x-windows (36 floats, static idx) + 4 float4 acc ~= 200 VGPR.
// __launch_bounds__(256,2): cap 256 VGPR (working set fits; R2's 4-wave cap
// at 64 VGPR caused 2.3 GB of scratch spill -- do NOT tighten this).
#define RC      256
#define BR      32
#define VROWS   K_FIX
#define VW_W    (RC + 32)            // 288 floats per LDS row
#define NRT     (N_DIM / RC)         // 12 r-tiles

__global__ __launch_bounds__(256, 2)
void fc_diag_fast(const float* __restrict__ x, const float* __restrict__ V,
                  const int* __restrict__ dp, float* __restrict__ out)
{
    // Wave-uniform pattern check (uniform across block -> safe w.r.t. barrier).
    bool ok = true;
    #pragma unroll
    for (int i = 0; i < K_FIX; ++i) ok = ok && (dp[i] == i);
    if (!ok) return;

    __shared__ float Vs[VROWS * VW_W];   // 34.56 KB

    const int rtile = blockIdx.x % NRT;
    const int btile = blockIdx.x / NRT;
    const int C0 = rtile * RC;
    const int b0 = btile * BR;

    // Stage pre-shifted V: Vs[i][m] = V[i][(C0 + m - 32 - i) mod N], so reads
    // at use-site are 16B-aligned ds_read_b128 regardless of diagonal i.
    for (int t = (int)threadIdx.x; t < VROWS * VW_W; t += 256) {
        const int i = t / VW_W;
        const int m = t - i * VW_W;
        int col = C0 + m - 32 - i;           // range [-61, 3071]
        if (col < 0) col += N_DIM;
        Vs[t] = V[(size_t)i * N_DIM + col];
    }
    __syncthreads();

    const int cg  = (int)threadIdx.x & 63;   // 64 x 4 cols = 256
    const int rg  = (int)threadIdx.x >> 6;   // 4 x 8 rows = 32
    const int c0l = cg * 4;
    const float* vbase = &Vs[c0l + 32];      // 16B-aligned, row stride VW_W

    #pragma unroll 1
    for (int it = 0; it < 2; ++it) {
        const int b = b0 + rg * 8 + it * 4;
        const float* xb0 = x + (size_t)b * N_DIM;
        const float* xb1 = xb0 + N_DIM;
        const float* xb2 = xb1 + N_DIM;
        const float* xb3 = xb2 + N_DIM;

        // 36 independent float4 loads; windows cover cols [C-32, C+4).
        float X0[36], X1[36], X2[36], X3[36];
        #pragma unroll
        for (int k = 0; k < 9; ++k) {
            int g = C0 + c0l - 32 + 4 * k;   // range [-32, 3068]
            if (g < 0) g += N_DIM;
            const float4 a = *reinterpret_cast<const float4*>(xb0 + g);
            const float4 c = *reinterpret_cast<const float4*>(xb1 + g);
            const float4 e = *reinterpret_cast<const float4*>(xb2 + g);
            const float4 f = *reinterpret_cast<const float4*>(xb3 + g);
            X0[4*k+0] = a.x; X0[4*k+1] = a.y; X0[4*k+2] = a.z; X0[4*k+3] = a.w;
            X1[4*k+0] = c.x; X1[4*k+1] = c.y; X1[4*k+2] = c.z; X1[4*k+3] = c.w;
            X2[4*k+0] = e.x; X2[4*k+1] = e.y; X2[4*k+2] = e.z; X2[4*k+3] = e.w;
            X3[4*k+0] = f.x; X3[4*k+1] = f.y; X3[4*k+2] = f.z; X3[4*k+3] = f.w;
        }

        float4 A0 = {0,0,0,0}, A1 = {0,0,0,0}, A2 = {0,0,0,0}, A3 = {0,0,0,0};
        #pragma unroll
        for (int i = 0; i < K_FIX; ++i) {
            const float4 vw = *reinterpret_cast<const float4*>(vbase + i * VW_W);
            // X index 32+j-i is a compile-time constant in [3,35].
            A0.x = fmaf(X0[32 - i], vw.x, A0.x);
            A0.y = fmaf(X0[33 - i], vw.y, A0.y);
            A0.z = fmaf(X0[34 - i], vw.z, A0.z);
            A0.w = fmaf(X0[35 - i], vw.w, A0.w);
            A1.x = fmaf(X1[32 - i], vw.x, A1.x);
            A1.y = fmaf(X1[33 - i], vw.y, A1.y);
            A1.z = fmaf(X1[34 - i], vw.z, A1.z);
            A1.w = fmaf(X1[35 - i], vw.w, A1.w);
            A2.x = fmaf(X2[32 - i], vw.x, A2.x);
            A2.y = fmaf(X2[33 - i], vw.y, A2.y);
            A2.z = fmaf(X2[34 - i], vw.z, A2.z);
            A2.w = fmaf(X2[35 - i], vw.w, A2.w);
            A3.x = fmaf(X3[32 - i], vw.x, A3.x);
            A3.y = fmaf(X3[33 - i], vw.y, A3.y);
            A3.z = fmaf(X3[34 - i], vw.z, A3.z);
            A3.w = fmaf(X3[35 - i], vw.w, A3.w);
        }

        float* ob = out + (size_t)b * N_DIM + C0 + c0l;
        *reinterpret_cast<float4*>(ob)             = A0;
        *reinterpret_cast<float4*>(ob + N_DIM)     = A1;
        *reinterpret_cast<float4*>(ob + 2 * N_DIM) = A2;
        *reinterpret_cast<float4*>(ob + 3 * N_DIM) = A3;
    }
}

// ---------------- Path 2: general K=30 (arbitrary diag values) --------------
#define G_NBT   128
#define G_BROWS (BATCH_N / G_NBT)    // 64

__global__ __launch_bounds__(256)
void fc_diag_general30(const float* __restrict__ x, const float* __restrict__ V,
                       const int* __restrict__ dp, float* __restrict__ out)
{
    bool contig = true;
    #pragma unroll
    for (int i = 0; i < K_FIX; ++i) contig = contig && (dp[i] == i);
    if (contig) return;  // fast kernel handled it

    const int NRT2 = N_DIM / 256;    // 12 r-tiles
    const int rtile = blockIdx.x % NRT2;
    const int btile = blockIdx.x / NRT2;
    const int r  = rtile * 256 + (int)threadIdx.x;
    const int b0 = btile * G_BROWS;

    int   CI[K_FIX];
    float VW[K_FIX];
    #pragma unroll
    for (int i = 0; i < K_FIX; ++i) {
        int d = dp[i] % N_DIM; if (d < 0) d += N_DIM;
        int c = r - d; if (c < 0) c += N_DIM;
        CI[i] = c;
        VW[i] = V[(size_t)d * N_DIM + c];
    }

    for (int b = b0; b < b0 + G_BROWS; b += 2) {
        const float* xb0 = x + (size_t)b * N_DIM;
        const float* xb1 = xb0 + N_DIM;
        float a0 = 0.f, a1 = 0.f;
        #pragma unroll
        for (int i = 0; i < K_FIX; ++i) {
            const float w = VW[i]; const int c = CI[i];
            a0 = fmaf(xb0[c], w, a0);
            a1 = fmaf(xb1[c], w, a1);
        }
        out[(size_t)b * N_DIM + r]       = a0;
        out[(size_t)(b + 1) * N_DIM + r] = a1;
    }
}

// ---------------- Path 3: naive fallback for K != 30 ------------------------
__global__ void fc_diag_naive(const float* __restrict__ x, const float* __restrict__ V,
                              const int* __restrict__ dp, int K, float* __restrict__ out)
{
    size_t idx   = (size_t)blockIdx.x * blockDim.x + threadIdx.x;
    size_t total = (size_t)BATCH_N * N_DIM;
    size_t step  = (size_t)gridDim.x * blockDim.x;
    for (; idx < total; idx += step) {
        int b = (int)(idx / N_DIM), r = (int)(idx % N_DIM);
        float acc = 0.f;
        for (int i = 0; i < K; ++i) {
            int d = dp[i] % N_DIM; if (d < 0) d += N_DIM;
            int c = r - d; if (c < 0) c += N_DIM;
            acc = fmaf(x[(size_t)b * N_DIM + c], V[(size_t)d * N_DIM + c], acc);
        }
        out[idx] = acc;
    }
}

extern "C" void kernel_launch(void* const* d_in, const int* in_sizes, int n_in,
                              void* d_out, int out_size, void* d_ws, size_t ws_size,
                              hipStream_t stream)
{
    const float* x  = (const float*)d_in[0];
    const float* V  = (const float*)d_in[1];
    const int*   dp = (const int*)d_in[2];
    float* out = (float*)d_out;
    const int K = in_sizes[2];

    if (K == K_FIX) {
        fc_diag_fast<<<dim3(NRT * (BATCH_N / BR)), dim3(256), 0, stream>>>(x, V, dp, out);
        fc_diag_general30<<<dim3((N_DIM / 256) * G_NBT), dim3(256), 0, stream>>>(x, V, dp, out);
    } else {
        fc_diag_naive<<<dim3(2048), dim3(256), 0, stream>>>(x, V, dp, K, out);
    }
}

// Round 5
// 101.650 us; speedup vs baseline: 6.9275x; 1.0809x over previous
//
#include <hip/hip_runtime.h>

#define N_DIM   3072
#define BATCH_N 8192
#define K_FIX   30

// ---------------- Path 1: specialized fast kernel (diag_pos[i] == i) --------
// GEMM-style staging: x tiles go global -> (regs) -> double-buffered LDS with
// a T14 async split (issue loads, compute current chunk, ds_write, barrier).
// V band is staged once (pre-shifted, LDS) then held in REGISTERS VW[30][4]
// per thread (static indices). Consume path touches only LDS (~120cyc) and
// VALU; global latency is hidden behind each chunk's 480-cyc FMA burst.
// Budgets: HBM 25us, LDS-read ~17us, VALU ~12us.
#define RC      256
#define PADW    (RC + 32)            // 288 floats per padded row (V and X)
#define BR      8                    // batch rows per chunk
#define NC      16                   // chunks per block
#define RPB     (BR * NC)            // 128 rows per block
#define NBT     (BATCH_N / RPB)      // 64
#define NRT     (N_DIM / RC)         // 12
#define XCHUNK_F4  (BR * PADW / 4)   // 576 float4 per chunk

__global__ __launch_bounds__(256, 2)
void fc_diag_fast(const float* __restrict__ x, const float* __restrict__ V,
                  const int* __restrict__ dp, float* __restrict__ out)
{
    bool ok = true;
    #pragma unroll
    for (int i = 0; i < K_FIX; ++i) ok = ok && (dp[i] == i);
    if (!ok) return;

    __shared__ float Vs[K_FIX * PADW];      // 34560 B
    __shared__ float Xs[2][BR * PADW];      // 18432 B  (total 52,992 B)

    const int rtile = blockIdx.x % NRT;
    const int btile = blockIdx.x / NRT;
    const int C0 = rtile * RC;
    const int b0 = btile * RPB;
    const int tid = (int)threadIdx.x;

    // ---- stage pre-shifted V band: Vs[i][m] = V[i][(C0 + m - 32 - i) mod N]
    for (int t = tid; t < K_FIX * PADW; t += 256) {
        const int i = t / PADW;
        const int m = t - i * PADW;
        int col = C0 + m - 32 - i;          // range [-61, 3071]
        if (col < 0) col += N_DIM;
        Vs[t] = V[(size_t)i * N_DIM + col];
    }
    __syncthreads();

    const int cg  = tid & 63;               // 64 x 4 cols
    const int rg  = tid >> 6;               // 4 x 2 rows per chunk
    const int c0l = cg * 4;

    // ---- pull V fragment into registers (static indices, lives whole kernel)
    float VW[K_FIX][4];
    #pragma unroll
    for (int i = 0; i < K_FIX; ++i) {
        const float4 vw = *reinterpret_cast<const float4*>(&Vs[i * PADW + c0l + 32]);
        VW[i][0] = vw.x; VW[i][1] = vw.y; VW[i][2] = vw.z; VW[i][3] = vw.w;
    }

    // ---- staging helpers (inline): thread t covers f4 indices t, t+256,
    //      and (t<64) t+512 of the 576-float4 chunk.
    float4 st0, st1, st2;
    const int i0r = tid / 72,          i0m = tid - i0r * 72;
    const int i1r = (tid + 256) / 72,  i1m = (tid + 256) - i1r * 72;
    const int i2r = (tid + 512) / 72,  i2m = (tid + 512) - i2r * 72;
    int g0 = C0 - 32 + 4 * i0m; if (g0 < 0) g0 += N_DIM;
    int g1 = C0 - 32 + 4 * i1m; if (g1 < 0) g1 += N_DIM;
    int g2 = C0 - 32 + 4 * i2m; if (g2 < 0) g2 += N_DIM;

#define STAGE_LOAD(c)                                                          \
    {                                                                          \
        const float* xb = x + (size_t)(b0 + (c) * BR) * N_DIM;                 \
        st0 = *reinterpret_cast<const float4*>(xb + (size_t)i0r * N_DIM + g0); \
        st1 = *reinterpret_cast<const float4*>(xb + (size_t)i1r * N_DIM + g1); \
        if (tid < 64)                                                          \
            st2 = *reinterpret_cast<const float4*>(xb + (size_t)i2r * N_DIM + g2); \
        asm volatile("" :: "v"(st0.x), "v"(st1.x));                            \
    }

#define STAGE_WRITE(s)                                                         \
    {                                                                          \
        *reinterpret_cast<float4*>(&Xs[s][4 * tid])        = st0;              \
        *reinterpret_cast<float4*>(&Xs[s][4 * (tid + 256)]) = st1;             \
        if (tid < 64)                                                          \
            *reinterpret_cast<float4*>(&Xs[s][4 * (tid + 512)]) = st2;         \
    }

    // prologue: fill buffer 0
    STAGE_LOAD(0);
    STAGE_WRITE(0);
    __syncthreads();

    #pragma unroll 1
    for (int c = 0; c < NC; ++c) {
        const int s = c & 1;
        if (c + 1 < NC) STAGE_LOAD(c + 1);

        // compute 2 rows x 4 cols from Xs[s]
        #pragma unroll
        for (int r2 = 0; r2 < 2; ++r2) {
            const int row = rg * 2 + r2;
            const float* xr = &Xs[s][row * PADW + c0l];   // X[m] = x[C0-32+c0l+m]
            float X[36];
            #pragma unroll
            for (int k = 0; k < 9; ++k) {
                const float4 v = *reinterpret_cast<const float4*>(xr + 4 * k);
                X[4*k+0] = v.x; X[4*k+1] = v.y; X[4*k+2] = v.z; X[4*k+3] = v.w;
            }
            float4 A = {0.f, 0.f, 0.f, 0.f};
            #pragma unroll
            for (int i = 0; i < K_FIX; ++i) {
                A.x = fmaf(X[32 - i], VW[i][0], A.x);
                A.y = fmaf(X[33 - i], VW[i][1], A.y);
                A.z = fmaf(X[34 - i], VW[i][2], A.z);
                A.w = fmaf(X[35 - i], VW[i][3], A.w);
            }
            const int b = b0 + c * BR + row;
            *reinterpret_cast<float4*>(out + (size_t)b * N_DIM + C0 + c0l) = A;
        }

        if (c + 1 < NC) STAGE_WRITE(s ^ 1);
        __syncthreads();
    }
#undef STAGE_LOAD
#undef STAGE_WRITE
}

// ---------------- Path 2: general K=30 (arbitrary diag values) --------------
#define G_NBT   128
#define G_BROWS (BATCH_N / G_NBT)    // 64

__global__ __launch_bounds__(256)
void fc_diag_general30(const float* __restrict__ x, const float* __restrict__ V,
                       const int* __restrict__ dp, float* __restrict__ out)
{
    bool contig = true;
    #pragma unroll
    for (int i = 0; i < K_FIX; ++i) contig = contig && (dp[i] == i);
    if (contig) return;  // fast kernel handled it

    const int NRT2 = N_DIM / 256;
    const int rtile = blockIdx.x % NRT2;
    const int btile = blockIdx.x / NRT2;
    const int r  = rtile * 256 + (int)threadIdx.x;
    const int b0 = btile * G_BROWS;

    int   CI[K_FIX];
    float VW[K_FIX];
    #pragma unroll
    for (int i = 0; i < K_FIX; ++i) {
        int d = dp[i] % N_DIM; if (d < 0) d += N_DIM;
        int c = r - d; if (c < 0) c += N_DIM;
        CI[i] = c;
        VW[i] = V[(size_t)d * N_DIM + c];
    }

    for (int b = b0; b < b0 + G_BROWS; b += 2) {
        const float* xb0 = x + (size_t)b * N_DIM;
        const float* xb1 = xb0 + N_DIM;
        float a0 = 0.f, a1 = 0.f;
        #pragma unroll
        for (int i = 0; i < K_FIX; ++i) {
            const float w = VW[i]; const int c = CI[i];
            a0 = fmaf(xb0[c], w, a0);
            a1 = fmaf(xb1[c], w, a1);
        }
        out[(size_t)b * N_DIM + r]       = a0;
        out[(size_t)(b + 1) * N_DIM + r] = a1;
    }
}

// ---------------- Path 3: naive fallback for K != 30 ------------------------
__global__ void fc_diag_naive(const float* __restrict__ x, const float* __restrict__ V,
                              const int* __restrict__ dp, int K, float* __restrict__ out)
{
    size_t idx   = (size_t)blockIdx.x * blockDim.x + threadIdx.x;
    size_t total = (size_t)BATCH_N * N_DIM;
    size_t step  = (size_t)gridDim.x * blockDim.x;
    for (; idx < total; idx += step) {
        int b = (int)(idx / N_DIM), r = (int)(idx % N_DIM);
        float acc = 0.f;
        for (int i = 0; i < K; ++i) {
            int d = dp[i] % N_DIM; if (d < 0) d += N_DIM;
            int c = r - d; if (c < 0) c += N_DIM;
            acc = fmaf(x[(size_t)b * N_DIM + c], V[(size_t)d * N_DIM + c], acc);
        }
        out[idx] = acc;
    }
}

extern "C" void kernel_launch(void* const* d_in, const int* in_sizes, int n_in,
                              void* d_out, int out_size, void* d_ws, size_t ws_size,
                              hipStream_t stream)
{
    const float* x  = (const float*)d_in[0];
    const float* V  = (const float*)d_in[1];
    const int*   dp = (const int*)d_in[2];
    float* out = (float*)d_out;
    const int K = in_sizes[2];

    if (K == K_FIX) {
        fc_diag_fast<<<dim3(NRT * NBT), dim3(256), 0, stream>>>(x, V, dp, out);
        fc_diag_general30<<<dim3((N_DIM / 256) * G_NBT), dim3(256), 0, stream>>>(x, V, dp, out);
    } else {
        fc_diag_naive<<<dim3(2048), dim3(256), 0, stream>>>(x, V, dp, K, out);
    }
}

// Round 6
// 60.786 us; speedup vs baseline: 11.5847x; 1.6723x over previous
//
#include <hip/hip_runtime.h>

#define N_DIM   3072
#define BATCH_N 8192
#define K_FIX   30

typedef __attribute__((ext_vector_type(8))) short  short8v;   // 8 bf16 (4 VGPR)
typedef __attribute__((ext_vector_type(4))) float  f32x4;
typedef __attribute__((ext_vector_type(4))) unsigned short ushort4v;

static __device__ __forceinline__ unsigned short f2bf(float f) {
    unsigned int u = __float_as_uint(f);
    u += 0x7fffu + ((u >> 16) & 1u);      // RNE
    return (unsigned short)(u >> 16);
}

// ---------------- Path 1: MFMA band-GEMM (diag_pos[i] == i) -----------------
// out[b, r] = sum_i x[b, r-i]*V[i, r-i]  ==>  per 16-col group starting cg0:
//   D[16 rows][16 cols] = A[16][64] * B[64][16],
//   A[row][k] = x[b0+row, (cg0-48+k) mod N],  B[k][j] = V[i][c], i = j+48-k,
//   nonzero iff i in [0,30)  (2 K-steps of mfma_f32_16x16x32_bf16).
// B-frags: built ONCE per block from V, 16 VGPR/wave. A: double-buffered bf16
// LDS tile [32 rows][304 cols] (pad 312 -> 624B rows, 16B aligned). Consume
// path = ds_read_b128 + MFMA only; global latency lives only in staging.
#define RC     256                    // out cols per block
#define XC     304                    // staged x cols: [C0-48, C0+256)
#define XP     312                    // padded row length (ushort)
#define NCH    4                      // chunks per block
#define CROWS  32                     // batch rows per chunk
#define NBT    (BATCH_N / (NCH * CROWS))   // 64
#define NRT    (N_DIM / RC)                // 12
#define NF4    (CROWS * XC / 4)            // 2432 float4 per chunk

__global__ __launch_bounds__(512)
void fc_diag_mfma(const float* __restrict__ x, const float* __restrict__ V,
                  const int* __restrict__ dp, float* __restrict__ out)
{
    bool ok = true;
    #pragma unroll
    for (int i = 0; i < K_FIX; ++i) ok = ok && (dp[i] == i);
    if (!ok) return;

    __shared__ unsigned short Xs[2][CROWS * XP];   // 2 x 19,968 B

    const int tid   = (int)threadIdx.x;
    const int rtile = blockIdx.x % NRT;
    const int btile = blockIdx.x / NRT;
    const int C0 = rtile * RC;
    const int b0 = btile * (NCH * CROWS);
    const int lane = tid & 63;
    const int w    = tid >> 6;          // wave id: owns cols [C0+32w, C0+32w+32)
    const int jloc = lane & 15;         // local col / A row
    const int lq   = lane >> 4;         // lane quarter

    // ---- B fragments (band of W^T), once per block, 16 VGPR ----
    short8v Bf[2][2];                   // [g][ks]
    #pragma unroll
    for (int g = 0; g < 2; ++g) {
        const int cg0 = C0 + w * 32 + g * 16;
        #pragma unroll
        for (int ks = 0; ks < 2; ++ks) {
            #pragma unroll
            for (int jj = 0; jj < 8; ++jj) {
                const int k = ks * 32 + lq * 8 + jj;
                const int i = jloc + 48 - k;
                unsigned short v = 0;
                if (i >= 0 && i < K_FIX) {
                    int c = cg0 + jloc - i;
                    if (c < 0) c += N_DIM;
                    v = f2bf(V[(size_t)i * N_DIM + c]);
                }
                Bf[g][ks][jj] = (short)v;
            }
        }
    }

    // ---- staging (T14 split): global f32 -> regs -> bf16 LDS ----
    float4 ld[5];
    int srow[5], sm4[5], sg[5];
    #pragma unroll
    for (int u = 0; u < 5; ++u) {
        const int idx = tid + u * 512;
        if (idx < NF4) {
            srow[u] = idx / 76;
            sm4[u]  = idx - srow[u] * 76;
            int c = C0 - 48 + 4 * sm4[u];
            if (c < 0) c += N_DIM;
            sg[u] = c;
        }
    }

#define STAGE_LOAD(ch)                                                         \
    {                                                                          \
        const float* xb = x + (size_t)(b0 + (ch) * CROWS) * N_DIM;             \
        _Pragma("unroll")                                                      \
        for (int u = 0; u < 5; ++u)                                            \
            if (tid + u * 512 < NF4)                                           \
                ld[u] = *reinterpret_cast<const float4*>(                      \
                    xb + (size_t)srow[u] * N_DIM + sg[u]);                     \
    }

#define STAGE_WRITE(s)                                                         \
    {                                                                          \
        _Pragma("unroll")                                                      \
        for (int u = 0; u < 5; ++u)                                            \
            if (tid + u * 512 < NF4) {                                         \
                ushort4v h;                                                    \
                h.x = f2bf(ld[u].x); h.y = f2bf(ld[u].y);                      \
                h.z = f2bf(ld[u].z); h.w = f2bf(ld[u].w);                      \
                *reinterpret_cast<ushort4v*>(&Xs[s][srow[u] * XP + 4 * sm4[u]]) = h; \
            }                                                                  \
    }

    STAGE_LOAD(0);
    STAGE_WRITE(0);
    __syncthreads();

    #pragma unroll 1
    for (int ch = 0; ch < NCH; ++ch) {
        const int s = ch & 1;
        if (ch + 1 < NCH) STAGE_LOAD(ch + 1);

        f32x4 acc[2][2];
        #pragma unroll
        for (int rh = 0; rh < 2; ++rh)
            #pragma unroll
            for (int g = 0; g < 2; ++g)
                acc[rh][g] = (f32x4){0.f, 0.f, 0.f, 0.f};

        #pragma unroll
        for (int g = 0; g < 2; ++g) {
            #pragma unroll
            for (int ks = 0; ks < 2; ++ks) {
                const int m0 = w * 32 + g * 16 + ks * 32 + lq * 8;  // <= 296
                #pragma unroll
                for (int rh = 0; rh < 2; ++rh) {
                    const int row = rh * 16 + jloc;
                    short8v a = *reinterpret_cast<const short8v*>(
                        &Xs[s][row * XP + m0]);
                    acc[rh][g] = __builtin_amdgcn_mfma_f32_16x16x32_bf16(
                        a, Bf[g][ks], acc[rh][g], 0, 0, 0);
                }
            }
        }

        // C/D layout (m89): col = lane&15, row = (lane>>4)*4 + reg
        #pragma unroll
        for (int rh = 0; rh < 2; ++rh)
            #pragma unroll
            for (int g = 0; g < 2; ++g)
                #pragma unroll
                for (int reg = 0; reg < 4; ++reg) {
                    const int bb = b0 + ch * CROWS + rh * 16 + lq * 4 + reg;
                    out[(size_t)bb * N_DIM + C0 + w * 32 + g * 16 + jloc] =
                        acc[rh][g][reg];
                }

        if (ch + 1 < NCH) STAGE_WRITE((ch + 1) & 1);
        __syncthreads();
    }
#undef STAGE_LOAD
#undef STAGE_WRITE
}

// ---------------- Path 2: general K=30 (arbitrary diag values) --------------
#define G_NBT   128
#define G_BROWS (BATCH_N / G_NBT)    // 64

__global__ __launch_bounds__(256)
void fc_diag_general30(const float* __restrict__ x, const float* __restrict__ V,
                       const int* __restrict__ dp, float* __restrict__ out)
{
    bool contig = true;
    #pragma unroll
    for (int i = 0; i < K_FIX; ++i) contig = contig && (dp[i] == i);
    if (contig) return;  // fast kernel handled it

    const int NRT2 = N_DIM / 256;
    const int rtile = blockIdx.x % NRT2;
    const int btile = blockIdx.x / NRT2;
    const int r  = rtile * 256 + (int)threadIdx.x;
    const int b0 = btile * G_BROWS;

    int   CI[K_FIX];
    float VW[K_FIX];
    #pragma unroll
    for (int i = 0; i < K_FIX; ++i) {
        int d = dp[i] % N_DIM; if (d < 0) d += N_DIM;
        int c = r - d; if (c < 0) c += N_DIM;
        CI[i] = c;
        VW[i] = V[(size_t)d * N_DIM + c];
    }

    for (int b = b0; b < b0 + G_BROWS; b += 2) {
        const float* xb0 = x + (size_t)b * N_DIM;
        const float* xb1 = xb0 + N_DIM;
        float a0 = 0.f, a1 = 0.f;
        #pragma unroll
        for (int i = 0; i < K_FIX; ++i) {
            const float w = VW[i]; const int c = CI[i];
            a0 = fmaf(xb0[c], w, a0);
            a1 = fmaf(xb1[c], w, a1);
        }
        out[(size_t)b * N_DIM + r]       = a0;
        out[(size_t)(b + 1) * N_DIM + r] = a1;
    }
}

// ---------------- Path 3: naive fallback for K != 30 ------------------------
__global__ void fc_diag_naive(const float* __restrict__ x, const float* __restrict__ V,
                              const int* __restrict__ dp, int K, float* __restrict__ out)
{
    size_t idx   = (size_t)blockIdx.x * blockDim.x + threadIdx.x;
    size_t total = (size_t)BATCH_N * N_DIM;
    size_t step  = (size_t)gridDim.x * blockDim.x;
    for (; idx < total; idx += step) {
        int b = (int)(idx / N_DIM), r = (int)(idx % N_DIM);
        float acc = 0.f;
        for (int i = 0; i < K; ++i) {
            int d = dp[i] % N_DIM; if (d < 0) d += N_DIM;
            int c = r - d; if (c < 0) c += N_DIM;
            acc = fmaf(x[(size_t)b * N_DIM + c], V[(size_t)d * N_DIM + c], acc);
        }
        out[idx] = acc;
    }
}

extern "C" void kernel_launch(void* const* d_in, const int* in_sizes, int n_in,
                              void* d_out, int out_size, void* d_ws, size_t ws_size,
                              hipStream_t stream)
{
    const float* x  = (const float*)d_in[0];
    const float* V  = (const float*)d_in[1];
    const int*   dp = (const int*)d_in[2];
    float* out = (float*)d_out;
    const int K = in_sizes[2];

    if (K == K_FIX) {
        fc_diag_mfma<<<dim3(NRT * NBT), dim3(512), 0, stream>>>(x, V, dp, out);
        fc_diag_general30<<<dim3((N_DIM / 256) * G_NBT), dim3(256), 0, stream>>>(x, V, dp, out);
    } else {
        fc_diag_naive<<<dim3(2048), dim3(256), 0, stream>>>(x, V, dp, K, out);
    }
}

// Round 7
// 55.452 us; speedup vs baseline: 12.6989x; 1.0962x over previous
//
#include <hip/hip_runtime.h>

#define N_DIM   3072
#define BATCH_N 8192
#define K_FIX   30

typedef __attribute__((ext_vector_type(8)))  short short8v;   // 8 bf16
typedef __attribute__((ext_vector_type(16))) float f32x16;

static __device__ __forceinline__ unsigned short f2bf(float f) {
    unsigned int u = __float_as_uint(f);
    u += 0x7fffu + ((u >> 16) & 1u);      // RNE
    return (unsigned short)(u >> 16);
}

static __device__ __forceinline__ short8v pack8(const float4 a, const float4 b) {
    short8v r;
    r[0] = (short)f2bf(a.x); r[1] = (short)f2bf(a.y);
    r[2] = (short)f2bf(a.z); r[3] = (short)f2bf(a.w);
    r[4] = (short)f2bf(b.x); r[5] = (short)f2bf(b.y);
    r[6] = (short)f2bf(b.z); r[7] = (short)f2bf(b.w);
    return r;
}

// ---------------- Path 1: barrier-free MFMA band-GEMM (diag_pos[i]==i) ------
// out[b, r] = sum_i x[b, r-i] * V[i, r-i].  Per wave: one 32-col group cg0,
// 256 batch rows as 8 chunks of 32.  D[32x32] = A[32x64] * B[64x32] via
// 4 x mfma_f32_32x32x16_bf16, where A[row][k] = x[b0+row, (cg0-32+k) mod N]
// and B[k][j] = V[i][(cg0-32+k) mod N], i = j+32-k, nonzero iff 3<=k-j+... i in [0,30).
// K0 = cg0-32 keeps every 8-col A segment 8-aligned and wrap-free.
// A frags load DIRECT from global (row-contiguous 8 f32 per lane, 2xfloat4),
// B lives in 16 VGPRs for the whole wave.  NO LDS, NO barriers -- every wave
// independent; latency hidden by 12 waves/CU TLP + 8 outstanding loads/wave.
// C/D layout (m74/m101): col = lane&31, row = (reg&3) + 8*(reg>>2) + 4*(lane>>5)
// -> stores are 128B contiguous segments (2x better than 16x16's 64B).
#define CG     32
#define NCG    (N_DIM / CG)          // 96 col groups
#define WROWS  256                   // rows per wave
#define NRG    (BATCH_N / WROWS)     // 32 row groups
#define NCHW   (WROWS / 32)          // 8 chunks per wave

__global__ __launch_bounds__(256)
void fc_diag_mfma32(const float* __restrict__ x, const float* __restrict__ V,
                    const int* __restrict__ dp, float* __restrict__ out)
{
    bool ok = true;
    #pragma unroll
    for (int i = 0; i < K_FIX; ++i) ok = ok && (dp[i] == i);
    if (!ok) return;

    const int lane = (int)threadIdx.x & 63;
    const int gw   = (int)blockIdx.x * 4 + ((int)threadIdx.x >> 6);
    const int cgi  = gw % NCG;           // 4 waves of a block -> adjacent col
    const int rgi  = gw / NCG;           // groups, same rows: L1/L2 reuse
    const int cg0  = cgi * CG;
    const int b0   = rgi * WROWS;
    const int j    = lane & 31;          // col within group / B col
    const int hi   = lane >> 5;

    // ---- B fragments (band of W^T), built once per wave, 16 VGPR ----
    // Bf[step][jj]: k = 16*step + hi*8 + jj, i = j + 32 - k.
    short8v Bf[4];
    #pragma unroll
    for (int step = 0; step < 4; ++step) {
        #pragma unroll
        for (int jj = 0; jj < 8; ++jj) {
            const int k = 16 * step + hi * 8 + jj;
            const int i = j + 32 - k;
            unsigned short v = 0;
            if (i >= 0 && i < K_FIX) {
                int c = cg0 - 32 + k;
                if (c < 0) c += N_DIM;
                v = f2bf(V[(size_t)i * N_DIM + c]);
            }
            Bf[step][jj] = (short)v;
        }
    }

    // per-lane A col base for step s: kbase + 16*s  (8-aligned; no mid-segment
    // wrap since kbase == 0 mod 8 and N_DIM == 0 mod 8)
    const int kbase = cg0 - 32 + hi * 8;

    #pragma unroll 1
    for (int ch = 0; ch < NCHW; ++ch) {
        const float* xr = x + (size_t)(b0 + ch * 32 + j) * N_DIM;

        // 8 independent float4 loads (A tile for this chunk)
        float4 la[4][2];
        #pragma unroll
        for (int step = 0; step < 4; ++step) {
            int c = kbase + 16 * step;
            if (c < 0) c += N_DIM;
            la[step][0] = *reinterpret_cast<const float4*>(xr + c);
            la[step][1] = *reinterpret_cast<const float4*>(xr + c + 4);
        }

        f32x16 acc = {0.f,0.f,0.f,0.f, 0.f,0.f,0.f,0.f,
                      0.f,0.f,0.f,0.f, 0.f,0.f,0.f,0.f};
        #pragma unroll
        for (int step = 0; step < 4; ++step) {
            const short8v a = pack8(la[step][0], la[step][1]);
            acc = __builtin_amdgcn_mfma_f32_32x32x16_bf16(a, Bf[step], acc, 0, 0, 0);
        }

        // C/D: col = lane&31 (=j), row = (reg&3) + 8*(reg>>2) + 4*hi
        float* ob = out + (size_t)(b0 + ch * 32) * N_DIM + cg0 + j;
        #pragma unroll
        for (int reg = 0; reg < 16; ++reg) {
            const int row = (reg & 3) + 8 * (reg >> 2) + 4 * hi;
            ob[(size_t)row * N_DIM] = acc[reg];
        }
    }
}

// ---------------- Path 2: general K=30 (arbitrary diag values) --------------
#define G_NBT   128
#define G_BROWS (BATCH_N / G_NBT)    // 64

__global__ __launch_bounds__(256)
void fc_diag_general30(const float* __restrict__ x, const float* __restrict__ V,
                       const int* __restrict__ dp, float* __restrict__ out)
{
    bool contig = true;
    #pragma unroll
    for (int i = 0; i < K_FIX; ++i) contig = contig && (dp[i] == i);
    if (contig) return;  // fast kernel handled it

    const int NRT2 = N_DIM / 256;
    const int rtile = blockIdx.x % NRT2;
    const int btile = blockIdx.x / NRT2;
    const int r  = rtile * 256 + (int)threadIdx.x;
    const int b0 = btile * G_BROWS;

    int   CI[K_FIX];
    float VW[K_FIX];
    #pragma unroll
    for (int i = 0; i < K_FIX; ++i) {
        int d = dp[i] % N_DIM; if (d < 0) d += N_DIM;
        int c = r - d; if (c < 0) c += N_DIM;
        CI[i] = c;
        VW[i] = V[(size_t)d * N_DIM + c];
    }

    for (int b = b0; b < b0 + G_BROWS; b += 2) {
        const float* xb0 = x + (size_t)b * N_DIM;
        const float* xb1 = xb0 + N_DIM;
        float a0 = 0.f, a1 = 0.f;
        #pragma unroll
        for (int i = 0; i < K_FIX; ++i) {
            const float w = VW[i]; const int c = CI[i];
            a0 = fmaf(xb0[c], w, a0);
            a1 = fmaf(xb1[c], w, a1);
        }
        out[(size_t)b * N_DIM + r]       = a0;
        out[(size_t)(b + 1) * N_DIM + r] = a1;
    }
}

// ---------------- Path 3: naive fallback for K != 30 ------------------------
__global__ void fc_diag_naive(const float* __restrict__ x, const float* __restrict__ V,
                              const int* __restrict__ dp, int K, float* __restrict__ out)
{
    size_t idx   = (size_t)blockIdx.x * blockDim.x + threadIdx.x;
    size_t total = (size_t)BATCH_N * N_DIM;
    size_t step  = (size_t)gridDim.x * blockDim.x;
    for (; idx < total; idx += step) {
        int b = (int)(idx / N_DIM), r = (int)(idx % N_DIM);
        float acc = 0.f;
        for (int i = 0; i < K; ++i) {
            int d = dp[i] % N_DIM; if (d < 0) d += N_DIM;
            int c = r - d; if (c < 0) c += N_DIM;
            acc = fmaf(x[(size_t)b * N_DIM + c], V[(size_t)d * N_DIM + c], acc);
        }
        out[idx] = acc;
    }
}

extern "C" void kernel_launch(void* const* d_in, const int* in_sizes, int n_in,
                              void* d_out, int out_size, void* d_ws, size_t ws_size,
                              hipStream_t stream)
{
    const float* x  = (const float*)d_in[0];
    const float* V  = (const float*)d_in[1];
    const int*   dp = (const int*)d_in[2];
    float* out = (float*)d_out;
    const int K = in_sizes[2];

    if (K == K_FIX) {
        // 3072 waves = 96 col-groups x 32 row-groups; 4 waves/block
        fc_diag_mfma32<<<dim3(NCG * NRG / 4), dim3(256), 0, stream>>>(x, V, dp, out);
        fc_diag_general30<<<dim3((N_DIM / 256) * G_NBT), dim3(256), 0, stream>>>(x, V, dp, out);
    } else {
        fc_diag_naive<<<dim3(2048), dim3(256), 0, stream>>>(x, V, dp, K, out);
    }
}